// Round 5
// baseline (12627.476 us; speedup 1.0000x reference)
//
#include <hip/hip_runtime.h>
#include <hip/hip_bf16.h>
#include <cstdint>
#include <cstddef>

#define B_ALL 256
#define T_SZ  1024

typedef __attribute__((ext_vector_type(8))) __bf16    bf16x8;
typedef __attribute__((ext_vector_type(4))) float     f32x4;
typedef __attribute__((ext_vector_type(4))) _Float16  halfx4;

__device__ __forceinline__ float sig_(float x) {
    return __builtin_amdgcn_rcpf(1.0f + __expf(-x));
}
__device__ __forceinline__ float tanh_(float x) {
    float ax = fabsf(x);
    float e  = __expf(-2.0f * ax);
    float t  = (1.0f - e) * __builtin_amdgcn_rcpf(1.0f + e);
    return copysignf(t, x);
}

__device__ __forceinline__ float bf2f_(unsigned short u) {
    union { unsigned int i; float f; } c; c.i = ((unsigned int)u) << 16; return c.f;
}
__device__ __forceinline__ float4 load4bf(const __hip_bfloat16* p) {
    unsigned long long v = *(const unsigned long long*)p;
    float4 f;
    f.x = bf2f_((unsigned short)v);
    f.y = bf2f_((unsigned short)(v >> 16));
    f.z = bf2f_((unsigned short)(v >> 32));
    f.w = bf2f_((unsigned short)(v >> 48));
    return f;
}

// ---------------- conv (causal, k=5) + relu -> X1[b_local][t][64] (bf16) ----------------
__global__ void conv_relu_kernel(const float* __restrict__ x, const float* __restrict__ w,
                                 const float* __restrict__ bias, __hip_bfloat16* __restrict__ out,
                                 int bg0)
{
    int c  = threadIdx.x & 63;
    int tq = threadIdx.x >> 6;
    int t  = blockIdx.x * 4 + tq;
    int b  = blockIdx.y;
    const float* xb = x + (size_t)(bg0 + b) * T_SZ;
    float s = bias[c];
#pragma unroll
    for (int k = 0; k < 5; ++k) {
        int ti = t - 4 + k;
        float xv = (ti >= 0) ? xb[ti] : 0.0f;
        s = fmaf(w[c * 5 + k], xv, s);
    }
    out[((size_t)b * T_SZ + t) * 64 + c] = __float2bfloat16(fmaxf(s, 0.0f));
}

// ---------------- chunked input-projection GEMM ----------------
// Output layout (fp16, gate-interleaved): out[dir][sl][b][hh*4 + gate]
// Block columns = 16 hh (blockIdx.y) x 4 gates. W-row remap in staging keeps
// the inner GEMM identical; epilogue stores are coalesced half4.
__global__ __launch_bounds__(256) void proj_kernel(
    const __hip_bfloat16* __restrict__ A, const float* __restrict__ W,
    const float* __restrict__ bias, _Float16* __restrict__ out,
    int K, int N, int lg /*log2 Tc*/, int t0, int Bg)
{
    int H4  = N >> 2;
    int dir = blockIdx.z;
    int Tc  = 1 << lg;
    W    += (size_t)dir * N * K;
    bias += (size_t)dir * N;
    out  += (size_t)dir * Tc * Bg * N;

    __shared__ float As[16][68];
    __shared__ float Ws[16][68];

    int tid = threadIdx.x;
    int tx = tid & 15, ty = tid >> 4;
    int m0  = blockIdx.x * 64;     // m = b*Tc + tl
    int hh0 = blockIdx.y * 16;

    float acc[4][4];
#pragma unroll
    for (int i = 0; i < 4; i++)
#pragma unroll
        for (int j = 0; j < 4; j++) acc[i][j] = 0.f;

    int li = tid >> 2;        // 0..63  (column c for Ws staging)
    int lk = (tid & 3) * 4;   // 0,4,8,12

    int mi = m0 + li;
    int bA = mi >> lg, tlA = mi & (Tc - 1);
    int tA = dir ? (T_SZ - 1 - (t0 + tlA)) : (t0 + tlA);
    const __hip_bfloat16* arow = A + ((size_t)bA * T_SZ + tA) * K;
    int nsel = (li & 3) * H4 + hh0 + (li >> 2);      // column c -> W row (gate=c&3, hh=hh0+c>>2)
    const float* wrow = W + (size_t)nsel * K;

    for (int k0 = 0; k0 < K; k0 += 16) {
        float4 av = load4bf(&arow[k0 + lk]);
        float4 wv = *(const float4*)&wrow[k0 + lk];
        As[lk + 0][li] = av.x; As[lk + 1][li] = av.y; As[lk + 2][li] = av.z; As[lk + 3][li] = av.w;
        Ws[lk + 0][li] = wv.x; Ws[lk + 1][li] = wv.y; Ws[lk + 2][li] = wv.z; Ws[lk + 3][li] = wv.w;
        __syncthreads();
#pragma unroll
        for (int kk = 0; kk < 16; ++kk) {
            float4 a4 = *(const float4*)&As[kk][ty * 4];
            float4 w4 = *(const float4*)&Ws[kk][tx * 4];
            float ar[4] = {a4.x, a4.y, a4.z, a4.w};
            float wr[4] = {w4.x, w4.y, w4.z, w4.w};
#pragma unroll
            for (int i = 0; i < 4; i++)
#pragma unroll
                for (int j = 0; j < 4; j++)
                    acc[i][j] = fmaf(ar[i], wr[j], acc[i][j]);
        }
        __syncthreads();
    }
#pragma unroll
    for (int i = 0; i < 4; i++) {
        int m = m0 + ty * 4 + i;
        int bO = m >> lg, tlO = m & (Tc - 1);
        halfx4 o;
#pragma unroll
        for (int j = 0; j < 4; j++)
            o[j] = (_Float16)(acc[i][j] + bias[j * H4 + hh0 + tx]);
        *(halfx4*)&out[((size_t)tlO * Bg + bO) * N + (size_t)(hh0 + tx) * 4] = o;
    }
}

// ---------------- MFMA LSTM recurrence ----------------
// Block: 16 batch rows, 1 direction, 256 threads (4 waves).
// xw: fp16 gate-interleaved [dir][sl][b][hh*4+gate]; per-lane 8B vector loads,
// prefetched one step ahead. h in LDS as bf16 hi/lo, double-buffered ->
// single barrier per step. W_hh bf16 B-frags register-resident. c in regs.
template <int H, bool WRITE_Y>
__global__ __launch_bounds__(256, 1) void lstm_rec_mfma(
    const _Float16* __restrict__ xw, const float* __restrict__ w_hh,
    __hip_bfloat16* __restrict__ y, float* __restrict__ lastOut,
    float* __restrict__ Hst, float* __restrict__ Cst,
    int Bg, int Tc, int step0, int zeroInit, int writeLast)
{
    constexpr int FH  = 4 * H;
    constexpr int KT  = H / 32;    // k-tiles of 32
    constexpr int NHB = H / 16;    // hh 16-blocks
    constexpr int Q   = NHB / 4;   // hh-blocks per wave (4 waves)
    constexpr int PAD = 8;

    const int dir = blockIdx.y;
    const int b0  = blockIdx.x * 16;
    const int tid = threadIdx.x;
    const int w   = tid >> 6;
    const int l   = tid & 63;
    const int l15 = l & 15;
    const int q4  = l >> 4;        // 0..3

    __shared__ __bf16 hAhi[2][16][H + PAD];
    __shared__ __bf16 hAlo[2][16][H + PAD];

    // ---- W_hh fragments (B-operand), fp32 -> bf16, register-resident ----
    bf16x8 wf[Q][4][KT];
    {
        const float* wbase = w_hh + (size_t)dir * FH * H;
#pragma unroll
        for (int q = 0; q < Q; ++q) {
            int qq = w * Q + q;
#pragma unroll
            for (int gate = 0; gate < 4; ++gate) {
                int n = gate * H + qq * 16 + l15;
#pragma unroll
                for (int kt = 0; kt < KT; ++kt) {
                    const float* src = wbase + (size_t)n * H + kt * 32 + q4 * 8;
                    float4 a = *(const float4*)(src);
                    float4 b = *(const float4*)(src + 4);
                    bf16x8 v;
                    v[0] = (__bf16)a.x; v[1] = (__bf16)a.y; v[2] = (__bf16)a.z; v[3] = (__bf16)a.w;
                    v[4] = (__bf16)b.x; v[5] = (__bf16)b.y; v[6] = (__bf16)b.z; v[7] = (__bf16)b.w;
                    wf[q][gate][kt] = v;
                }
            }
        }
    }

    // ---- init h (LDS buf 0) and c (regs) ----
    float creg[Q][4];
#pragma unroll
    for (int q = 0; q < Q; ++q) {
        int qq = w * Q + q;
        int hh = qq * 16 + l15;
#pragma unroll
        for (int r = 0; r < 4; ++r) {
            int m = q4 * 4 + r;
            float hv = 0.f, cv = 0.f;
            if (!zeroInit) {
                hv = Hst[((size_t)dir * Bg + b0 + m) * H + hh];
                cv = Cst[((size_t)dir * Bg + b0 + m) * H + hh];
            }
            creg[q][r] = cv;
            __bf16 hi = (__bf16)hv;
            hAhi[0][m][hh] = hi;
            hAlo[0][m][hh] = (__bf16)(hv - (float)hi);
        }
    }

    const _Float16* xwB = xw + (size_t)dir * Tc * Bg * FH;

    // prefetch xw for sl=0
    halfx4 pf[Q][4];
    {
        const _Float16* xrow = xwB;
#pragma unroll
        for (int q = 0; q < Q; ++q) {
            int hoff = ((w * Q + q) * 16 + l15) * 4;
#pragma unroll
            for (int r = 0; r < 4; ++r)
                pf[q][r] = *(const halfx4*)&xrow[(size_t)(b0 + q4 * 4 + r) * FH + hoff];
        }
    }
    __syncthreads();

    for (int sl = 0; sl < Tc; ++sl) {
        const int p = sl & 1;
        const int t = dir ? (T_SZ - 1 - (step0 + sl)) : (step0 + sl);

        bf16x8 ahi[KT], alo[KT];
#pragma unroll
        for (int kt = 0; kt < KT; ++kt) {
            ahi[kt] = *(const bf16x8*)&hAhi[p][l15][kt * 32 + q4 * 8];
            alo[kt] = *(const bf16x8*)&hAlo[p][l15][kt * 32 + q4 * 8];
        }

        f32x4 acc[Q][4];
#pragma unroll
        for (int q = 0; q < Q; ++q) {
#pragma unroll
            for (int gate = 0; gate < 4; ++gate) {
                f32x4 a = {0.f, 0.f, 0.f, 0.f};
#pragma unroll
                for (int kt = 0; kt < KT; ++kt) {
                    a = __builtin_amdgcn_mfma_f32_16x16x32_bf16(ahi[kt], wf[q][gate][kt], a, 0, 0, 0);
                    a = __builtin_amdgcn_mfma_f32_16x16x32_bf16(alo[kt], wf[q][gate][kt], a, 0, 0, 0);
                }
                acc[q][gate] = a;
            }
        }

        // prefetch next step's xw during MFMA drain
        halfx4 pf2[Q][4];
        if (sl + 1 < Tc) {
            const _Float16* xrow = xwB + (size_t)(sl + 1) * Bg * FH;
#pragma unroll
            for (int q = 0; q < Q; ++q) {
                int hoff = ((w * Q + q) * 16 + l15) * 4;
#pragma unroll
                for (int r = 0; r < 4; ++r)
                    pf2[q][r] = *(const halfx4*)&xrow[(size_t)(b0 + q4 * 4 + r) * FH + hoff];
            }
        }

#pragma unroll
        for (int q = 0; q < Q; ++q) {
            int qq = w * Q + q; int hh = qq * 16 + l15;
#pragma unroll
            for (int r = 0; r < 4; ++r) {
                int m = q4 * 4 + r;
                float iv = acc[q][0][r] + (float)pf[q][r][0];
                float fv = acc[q][1][r] + (float)pf[q][r][1];
                float gv = acc[q][2][r] + (float)pf[q][r][2];
                float ov = acc[q][3][r] + (float)pf[q][r][3];
                iv = fminf(fmaxf(iv, -25.f), 25.f);
                fv = fminf(fmaxf(fv, -25.f), 25.f);
                gv = fminf(fmaxf(gv, -12.f), 12.f);
                ov = fminf(fmaxf(ov, -25.f), 25.f);
                // c' = sig(f)*c + sig(i)*tanh(g), one rcp
                float Af = 1.f + __expf(-fv);
                float Bi = 1.f + __expf(-iv);
                float G  = __expf(2.f * gv);
                float Gp = G + 1.f, Gm = G - 1.f;
                float cv = creg[q][r];
                float num = fmaf(cv * Bi, Gp, Af * Gm);
                float cn  = num * __builtin_amdgcn_rcpf(Af * Bi * Gp);
                creg[q][r] = cn;
                // h = sig(o)*tanh(c'), one rcp
                float cc = fminf(fmaxf(cn, -25.f), 25.f);
                float E  = __expf(2.f * cc);
                float hv = (E - 1.f) * __builtin_amdgcn_rcpf((1.f + __expf(-ov)) * (E + 1.f));
                __bf16 hi = (__bf16)hv;
                hAhi[1 - p][m][hh] = hi;
                hAlo[1 - p][m][hh] = (__bf16)(hv - (float)hi);
                if (WRITE_Y) {
                    y[((size_t)(b0 + m) * T_SZ + t) * (2 * H) + dir * H + hh] = __float2bfloat16(hv);
                } else if (writeLast && sl == Tc - 1) {
                    lastOut[(b0 + m) * 128 + hh] = hv;
                }
                if (sl == Tc - 1) {
                    Hst[((size_t)dir * Bg + b0 + m) * H + hh] = hv;
                    Cst[((size_t)dir * Bg + b0 + m) * H + hh] = cn;
                }
            }
        }
#pragma unroll
        for (int q = 0; q < Q; ++q)
#pragma unroll
            for (int r = 0; r < 4; ++r) pf[q][r] = pf2[q][r];
        __syncthreads();
    }
}

// ---------------- layer-3 backward: exactly one step from zero state ----------------
__global__ __launch_bounds__(256) void lstm3_bwd_kernel(
    const __hip_bfloat16* __restrict__ y2, const float* __restrict__ w_ih3,
    const float* __restrict__ b3, float* __restrict__ H3)
{
    int b = blockIdx.x, g = threadIdx.x;
    __shared__ float xr[256];
    __shared__ float gsh[256];
    xr[g] = __bfloat162float(y2[((size_t)b * T_SZ + (T_SZ - 1)) * 256 + g]);
    __syncthreads();
    const float* wr = w_ih3 + (size_t)256 * 256 + (size_t)g * 256;  // dir 1
    float acc = b3[256 + g];
#pragma unroll 4
    for (int k = 0; k < 256; k++) acc = fmaf(wr[k], xr[k], acc);
    gsh[g] = acc;
    __syncthreads();
    if (g < 64) {
        float iv = gsh[g], gv = gsh[128 + g], ov = gsh[192 + g];
        float ct = sig_(iv) * tanh_(gv);   // c0 = 0 -> forget term vanishes
        float hv = sig_(ov) * tanh_(ct);
        H3[b * 128 + 64 + g] = hv;
    }
}

// ---------------- FC ----------------
__global__ void fc_kernel(const float* __restrict__ in, const float* __restrict__ W,
                          const float* __restrict__ bias, float* __restrict__ out,
                          int K, int N, int doRelu)
{
    int b = blockIdx.x;
    int g = threadIdx.x;
    extern __shared__ float xr[];
    for (int i = g; i < K; i += blockDim.x) xr[i] = in[(size_t)b * K + i];
    __syncthreads();
    if (g < N) {
        const float* wr = W + (size_t)g * K;
        float acc = bias[g];
        for (int k = 0; k < K; k++) acc = fmaf(wr[k], xr[k], acc);
        if (doRelu) acc = fmaxf(acc, 0.f);
        out[(size_t)b * N + g] = acc;
    }
}

extern "C" void kernel_launch(void* const* d_in, const int* in_sizes, int n_in,
                              void* d_out, int out_size, void* d_ws, size_t ws_size,
                              hipStream_t stream)
{
    (void)in_sizes; (void)n_in; (void)out_size;
    const float* x      = (const float*)d_in[0];
    const float* conv_w = (const float*)d_in[1];
    const float* conv_b = (const float*)d_in[2];
    const float* w_ih1  = (const float*)d_in[3];
    const float* w_hh1  = (const float*)d_in[4];
    const float* b1     = (const float*)d_in[5];
    const float* w_ih2  = (const float*)d_in[6];
    const float* w_hh2  = (const float*)d_in[7];
    const float* b2     = (const float*)d_in[8];
    const float* w_ih3  = (const float*)d_in[9];
    const float* w_hh3  = (const float*)d_in[10];
    const float* b3     = (const float*)d_in[11];
    const float* fc1_w  = (const float*)d_in[12];
    const float* fc1_b  = (const float*)d_in[13];
    const float* fc2_w  = (const float*)d_in[14];
    const float* fc2_b  = (const float*)d_in[15];
    const float* fc3_w  = (const float*)d_in[16];
    const float* fc3_b  = (const float*)d_in[17];
    const float* fc4_w  = (const float*)d_in[18];
    const float* fc4_b  = (const float*)d_in[19];
    float* out = (float*)d_out;
    char*  base = (char*)d_ws;

    const size_t MB = 1ull << 20;

    // footprint: 2 bf16 Y buffers + fp16 XW chunk + small
    auto need = [&](int s, int tc) -> size_t {
        size_t Bg = B_ALL / s;
        size_t YB = Bg * T_SZ * 256 * 2;                 // bf16 Y buffer
        size_t XW = (size_t)tc * Bg * 512 * 2 * 2;       // fp16 chunk, 2 dirs
        return 2 * YB + XW + 2 * MB;
    };

    int S = 8;
    for (int s : {1, 2, 4, 8}) {
        if (need(s, 16) <= ws_size) { S = s; break; }
    }
    int Tc = 16;
    while (Tc < 256 && need(S, Tc * 2) <= ws_size) Tc <<= 1;
    int lg = 0; while ((1 << lg) < Tc) lg++;
    int NC = T_SZ / Tc;

    int Bg = B_ALL / S;
    size_t YB = (size_t)Bg * T_SZ * 256 * 2;
    __hip_bfloat16* Y1 = (__hip_bfloat16*)base;
    __hip_bfloat16* Y2 = (__hip_bfloat16*)(base + YB);
    __hip_bfloat16* X1 = Y2;                             // aliased: X1 dead before Y2 written
    _Float16* XWc = (_Float16*)(base + 2 * YB);
    float* sm  = (float*)(base + 2 * YB + (size_t)Tc * Bg * 512 * 2 * 2);
    float* Hs = sm;                   // 2*Bg*128
    float* Cs = Hs + 2 * Bg * 128;
    float* H3 = Cs + 2 * Bg * 128;    // Bg*128
    float* F1 = H3 + Bg * 128;        // Bg*512
    float* F2 = F1 + Bg * 512;        // Bg*256
    float* F3 = F2 + Bg * 256;        // Bg*128

    for (int sp = 0; sp < S; ++sp) {
        int bg0 = sp * Bg;

        conv_relu_kernel<<<dim3(T_SZ / 4, Bg), 256, 0, stream>>>(x, conv_w, conv_b, X1, bg0);

        // layer 1 (D=64, H=128) : X1 -> Y1
        for (int ci = 0; ci < NC; ++ci) {
            proj_kernel<<<dim3(Bg * Tc / 64, 512 / 64, 2), 256, 0, stream>>>(
                X1, w_ih1, b1, XWc, 64, 512, lg, ci * Tc, Bg);
            lstm_rec_mfma<128, true><<<dim3(Bg / 16, 2), 256, 0, stream>>>(
                XWc, w_hh1, Y1, nullptr, Hs, Cs, Bg, Tc, ci * Tc, ci == 0, 0);
        }
        // layer 2 (D=256, H=128) : Y1 -> Y2
        for (int ci = 0; ci < NC; ++ci) {
            proj_kernel<<<dim3(Bg * Tc / 64, 512 / 64, 2), 256, 0, stream>>>(
                Y1, w_ih2, b2, XWc, 256, 512, lg, ci * Tc, Bg);
            lstm_rec_mfma<128, true><<<dim3(Bg / 16, 2), 256, 0, stream>>>(
                XWc, w_hh2, Y2, nullptr, Hs, Cs, Bg, Tc, ci * Tc, ci == 0, 0);
        }
        // layer 3 (D=256, H=64): forward full scan (final h only) + backward single step
        for (int ci = 0; ci < NC; ++ci) {
            proj_kernel<<<dim3(Bg * Tc / 64, 256 / 64, 1), 256, 0, stream>>>(
                Y2, w_ih3, b3, XWc, 256, 256, lg, ci * Tc, Bg);
            lstm_rec_mfma<64, false><<<dim3(Bg / 16, 1), 256, 0, stream>>>(
                XWc, w_hh3, nullptr, H3, Hs, Cs, Bg, Tc, ci * Tc, ci == 0, ci == NC - 1);
        }
        lstm3_bwd_kernel<<<Bg, 256, 0, stream>>>(Y2, w_ih3, b3, H3);

        fc_kernel<<<Bg, 512, 128 * 4, stream>>>(H3, fc1_w, fc1_b, F1, 128, 512, 1);
        fc_kernel<<<Bg, 256, 512 * 4, stream>>>(F1, fc2_w, fc2_b, F2, 512, 256, 1);
        fc_kernel<<<Bg, 128, 256 * 4, stream>>>(F2, fc3_w, fc3_b, F3, 256, 128, 1);
        fc_kernel<<<Bg, 64, 128 * 4, stream>>>(F3, fc4_w, fc4_b, out + (size_t)bg0 * 2, 128, 2, 0);
    }
}

// Round 6
// 9338.549 us; speedup vs baseline: 1.3522x; 1.3522x over previous
//
#include <hip/hip_runtime.h>
#include <hip/hip_bf16.h>
#include <cstdint>
#include <cstddef>

#define B_ALL 256
#define T_SZ  1024

typedef __attribute__((ext_vector_type(8))) __bf16    bf16x8;
typedef __attribute__((ext_vector_type(4))) __bf16    bf16x4;
typedef __attribute__((ext_vector_type(4))) float     f32x4;
typedef __attribute__((ext_vector_type(4))) _Float16  halfx4;

__device__ __forceinline__ float sig_(float x) {
    return __builtin_amdgcn_rcpf(1.0f + __expf(-x));
}
__device__ __forceinline__ float tanh_(float x) {
    float ax = fabsf(x);
    float e  = __expf(-2.0f * ax);
    float t  = (1.0f - e) * __builtin_amdgcn_rcpf(1.0f + e);
    return copysignf(t, x);
}

// ---------------- conv (causal, k=5) + relu -> X1[b_local][t][64] (bf16) ----------------
__global__ void conv_relu_kernel(const float* __restrict__ x, const float* __restrict__ w,
                                 const float* __restrict__ bias, __hip_bfloat16* __restrict__ out,
                                 int bg0)
{
    int c  = threadIdx.x & 63;
    int tq = threadIdx.x >> 6;
    int t  = blockIdx.x * 4 + tq;
    int b  = blockIdx.y;
    const float* xb = x + (size_t)(bg0 + b) * T_SZ;
    float s = bias[c];
#pragma unroll
    for (int k = 0; k < 5; ++k) {
        int ti = t - 4 + k;
        float xv = (ti >= 0) ? xb[ti] : 0.0f;
        s = fmaf(w[c * 5 + k], xv, s);
    }
    out[((size_t)b * T_SZ + t) * 64 + c] = __float2bfloat16(fmaxf(s, 0.0f));
}

// ---------------- MFMA input-projection GEMM ----------------
// C[m][o] = sum_k A[m_row(m)][k] * W[n_orig(o)][k] + bias[n_orig(o)]
// m = b*Tc + tl (t = t0+tl, reversed for dir=1); o = hh*4+gate (gate-interleaved),
// n_orig(o) = (o&3)*(N/4) + (o>>2). Output fp16 [dir][tl][b][o].
// Block: 128m x 128o tile, 256 threads (4 waves in 2x2 quadrant grid), BK=32.
__global__ __launch_bounds__(256, 2) void proj_mfma(
    const __hip_bfloat16* __restrict__ A, const float* __restrict__ W,
    const float* __restrict__ bias, _Float16* __restrict__ out,
    int K, int N, int lg /*log2 Tc*/, int t0, int Bg)
{
    const int H4  = N >> 2;
    const int Tc  = 1 << lg;
    const int dir = blockIdx.z;
    W    += (size_t)dir * N * K;
    bias += (size_t)dir * N;
    out  += (size_t)dir * Tc * Bg * N;

    __shared__ __bf16 As[128][40];   // 32 k + 8 pad (80B row, 16B-aligned)
    __shared__ __bf16 Ws[128][40];

    const int tid = threadIdx.x;
    const int w   = tid >> 6;
    const int l   = tid & 63;
    const int l15 = l & 15;
    const int q4  = l >> 4;
    const int m0  = blockIdx.x * 128;
    const int n0  = blockIdx.y * 128;
    const int wm  = (w & 1) * 64;
    const int wn  = (w >> 1) * 64;

    f32x4 acc[4][4];
#pragma unroll
    for (int i = 0; i < 4; i++)
#pragma unroll
        for (int j = 0; j < 4; j++) acc[i][j] = (f32x4){0.f, 0.f, 0.f, 0.f};

    for (int k0 = 0; k0 < K; k0 += 32) {
        // stage A: 128 rows x 32 bf16; 2 passes x 256 threads x 16B
#pragma unroll
        for (int pass = 0; pass < 2; ++pass) {
            int c2  = tid + pass * 256;
            int row = c2 >> 2;
            int ko  = (c2 & 3) * 8;
            int m   = m0 + row;
            int bA  = m >> lg, tl = m & (Tc - 1);
            int t   = dir ? (T_SZ - 1 - (t0 + tl)) : (t0 + tl);
            const __hip_bfloat16* src = A + ((size_t)bA * T_SZ + t) * K + k0 + ko;
            *(bf16x8*)&As[row][ko] = *(const bf16x8*)src;
        }
        // stage W: 128 rows x 32 fp32 -> bf16; 4 passes x 256 threads x float4
#pragma unroll
        for (int pass = 0; pass < 4; ++pass) {
            int c2  = tid + pass * 256;
            int row = c2 >> 3;
            int ko  = (c2 & 7) * 4;
            int n_o = n0 + row;
            int nr  = (n_o & 3) * H4 + (n_o >> 2);
            float4 f = *(const float4*)&W[(size_t)nr * K + k0 + ko];
            bf16x4 v;
            v[0] = (__bf16)f.x; v[1] = (__bf16)f.y; v[2] = (__bf16)f.z; v[3] = (__bf16)f.w;
            *(bf16x4*)&Ws[row][ko] = v;
        }
        __syncthreads();

        bf16x8 af[4], bf[4];
#pragma unroll
        for (int i = 0; i < 4; i++) af[i] = *(const bf16x8*)&As[wm + i * 16 + l15][q4 * 8];
#pragma unroll
        for (int j = 0; j < 4; j++) bf[j] = *(const bf16x8*)&Ws[wn + j * 16 + l15][q4 * 8];
#pragma unroll
        for (int i = 0; i < 4; i++)
#pragma unroll
            for (int j = 0; j < 4; j++)
                acc[i][j] = __builtin_amdgcn_mfma_f32_16x16x32_bf16(af[i], bf[j], acc[i][j], 0, 0, 0);
        __syncthreads();
    }

    // epilogue: D row m = q4*4+reg, col n = l15 (verified mapping)
#pragma unroll
    for (int i = 0; i < 4; i++) {
#pragma unroll
        for (int j = 0; j < 4; j++) {
            int n_o = n0 + wn + j * 16 + l15;
            float bi = bias[(n_o & 3) * H4 + (n_o >> 2)];
#pragma unroll
            for (int r = 0; r < 4; r++) {
                int m  = m0 + wm + i * 16 + q4 * 4 + r;
                int bA = m >> lg, tl = m & (Tc - 1);
                out[((size_t)tl * Bg + bA) * N + n_o] = (_Float16)(acc[i][j][r] + bi);
            }
        }
    }
}

// ---------------- MFMA LSTM recurrence v2 ----------------
// Block: 16 batch rows, 1 direction, NW waves (NW = H/16). Wave w owns hh-block w.
// xw: fp16 gate-interleaved [dir][sl][b][hh*4+gate]. W_hh bf16 B-frags reg-resident
// (64 VGPRs at H=128). h in LDS bf16 hi/lo double-buffered; c in regs; 1 barrier/step.
template <int H, int NW, bool WRITE_Y>
__global__ __launch_bounds__(NW * 64, 2) void lstm_rec_mfma(
    const _Float16* __restrict__ xw, const float* __restrict__ w_hh,
    __hip_bfloat16* __restrict__ y, float* __restrict__ lastOut,
    float* __restrict__ Hst, float* __restrict__ Cst,
    int Bg, int Tc, int step0, int zeroInit, int writeLast)
{
    constexpr int FH = 4 * H;
    constexpr int KT = H / 32;
    static_assert(NW == H / 16, "one hh-block per wave");

    const int dir = blockIdx.y;
    const int b0  = blockIdx.x * 16;
    const int tid = threadIdx.x;
    const int w   = tid >> 6;
    const int l   = tid & 63;
    const int l15 = l & 15;
    const int q4  = l >> 4;
    const int hh  = w * 16 + l15;

    __shared__ __bf16 hAhi[2][16][H + 8];
    __shared__ __bf16 hAlo[2][16][H + 8];

    // W_hh fragments: gate rows n = gate*H + hh, k = kt*32 + q4*8
    bf16x8 wf[4][KT];
    {
        const float* wbase = w_hh + (size_t)dir * FH * H;
#pragma unroll
        for (int gate = 0; gate < 4; ++gate) {
            const float* wrow = wbase + (size_t)(gate * H + hh) * H;
#pragma unroll
            for (int kt = 0; kt < KT; ++kt) {
                const float* src = wrow + kt * 32 + q4 * 8;
                float4 a = *(const float4*)(src);
                float4 b = *(const float4*)(src + 4);
                bf16x8 v;
                v[0] = (__bf16)a.x; v[1] = (__bf16)a.y; v[2] = (__bf16)a.z; v[3] = (__bf16)a.w;
                v[4] = (__bf16)b.x; v[5] = (__bf16)b.y; v[6] = (__bf16)b.z; v[7] = (__bf16)b.w;
                wf[gate][kt] = v;
            }
        }
    }

    // init h (LDS buf 0) and c (regs); lane owns (m = q4*4+r, hh)
    float creg[4];
#pragma unroll
    for (int r = 0; r < 4; ++r) {
        int m = q4 * 4 + r;
        float hv = 0.f, cv = 0.f;
        if (!zeroInit) {
            hv = Hst[((size_t)dir * Bg + b0 + m) * H + hh];
            cv = Cst[((size_t)dir * Bg + b0 + m) * H + hh];
        }
        creg[r] = cv;
        __bf16 hi = (__bf16)hv;
        hAhi[0][m][hh] = hi;
        hAlo[0][m][hh] = (__bf16)(hv - (float)hi);
    }

    const _Float16* xwB = xw + (size_t)dir * Tc * Bg * FH;
    const int hoff = hh * 4;

    halfx4 pf[4];
#pragma unroll
    for (int r = 0; r < 4; ++r)
        pf[r] = *(const halfx4*)&xwB[(size_t)(b0 + q4 * 4 + r) * FH + hoff];
    __syncthreads();

    for (int sl = 0; sl < Tc; ++sl) {
        const int p = sl & 1;
        const int t = dir ? (T_SZ - 1 - (step0 + sl)) : (step0 + sl);

        bf16x8 ahi[KT], alo[KT];
#pragma unroll
        for (int kt = 0; kt < KT; ++kt) {
            ahi[kt] = *(const bf16x8*)&hAhi[p][l15][kt * 32 + q4 * 8];
            alo[kt] = *(const bf16x8*)&hAlo[p][l15][kt * 32 + q4 * 8];
        }

        f32x4 acc[4];
#pragma unroll
        for (int gate = 0; gate < 4; ++gate) {
            f32x4 a = {0.f, 0.f, 0.f, 0.f};
#pragma unroll
            for (int kt = 0; kt < KT; ++kt) {
                a = __builtin_amdgcn_mfma_f32_16x16x32_bf16(ahi[kt], wf[gate][kt], a, 0, 0, 0);
                a = __builtin_amdgcn_mfma_f32_16x16x32_bf16(alo[kt], wf[gate][kt], a, 0, 0, 0);
            }
            acc[gate] = a;
        }

        halfx4 pf2[4];
        if (sl + 1 < Tc) {
            const _Float16* xrow = xwB + (size_t)(sl + 1) * Bg * FH;
#pragma unroll
            for (int r = 0; r < 4; ++r)
                pf2[r] = *(const halfx4*)&xrow[(size_t)(b0 + q4 * 4 + r) * FH + hoff];
        }

#pragma unroll
        for (int r = 0; r < 4; ++r) {
            int m = q4 * 4 + r;
            float iv = acc[0][r] + (float)pf[r][0];
            float fv = acc[1][r] + (float)pf[r][1];
            float gv = acc[2][r] + (float)pf[r][2];
            float ov = acc[3][r] + (float)pf[r][3];
            iv = fminf(fmaxf(iv, -25.f), 25.f);
            fv = fminf(fmaxf(fv, -25.f), 25.f);
            gv = fminf(fmaxf(gv, -12.f), 12.f);
            ov = fminf(fmaxf(ov, -25.f), 25.f);
            float Af = 1.f + __expf(-fv);
            float Bi = 1.f + __expf(-iv);
            float G  = __expf(2.f * gv);
            float Gp = G + 1.f, Gm = G - 1.f;
            float cv = creg[r];
            float num = fmaf(cv * Bi, Gp, Af * Gm);
            float cn  = num * __builtin_amdgcn_rcpf(Af * Bi * Gp);
            creg[r] = cn;
            float cc = fminf(fmaxf(cn, -25.f), 25.f);
            float E  = __expf(2.f * cc);
            float hv = (E - 1.f) * __builtin_amdgcn_rcpf((1.f + __expf(-ov)) * (E + 1.f));
            __bf16 hi = (__bf16)hv;
            hAhi[1 - p][m][hh] = hi;
            hAlo[1 - p][m][hh] = (__bf16)(hv - (float)hi);
            if (WRITE_Y) {
                y[((size_t)(b0 + m) * T_SZ + t) * (2 * H) + dir * H + hh] = __float2bfloat16(hv);
            } else if (writeLast && sl == Tc - 1) {
                lastOut[(b0 + m) * 128 + hh] = hv;
            }
            if (sl == Tc - 1) {
                Hst[((size_t)dir * Bg + b0 + m) * H + hh] = hv;
                Cst[((size_t)dir * Bg + b0 + m) * H + hh] = cn;
            }
        }
#pragma unroll
        for (int r = 0; r < 4; ++r) pf[r] = pf2[r];
        __syncthreads();
    }
}

// ---------------- layer-3 backward: exactly one step from zero state ----------------
__global__ __launch_bounds__(256) void lstm3_bwd_kernel(
    const __hip_bfloat16* __restrict__ y2, const float* __restrict__ w_ih3,
    const float* __restrict__ b3, float* __restrict__ H3)
{
    int b = blockIdx.x, g = threadIdx.x;
    __shared__ float xr[256];
    __shared__ float gsh[256];
    xr[g] = __bfloat162float(y2[((size_t)b * T_SZ + (T_SZ - 1)) * 256 + g]);
    __syncthreads();
    const float* wr = w_ih3 + (size_t)256 * 256 + (size_t)g * 256;  // dir 1
    float acc = b3[256 + g];
#pragma unroll 4
    for (int k = 0; k < 256; k++) acc = fmaf(wr[k], xr[k], acc);
    gsh[g] = acc;
    __syncthreads();
    if (g < 64) {
        float iv = gsh[g], gv = gsh[128 + g], ov = gsh[192 + g];
        float ct = sig_(iv) * tanh_(gv);   // c0 = 0 -> forget term vanishes
        float hv = sig_(ov) * tanh_(ct);
        H3[b * 128 + 64 + g] = hv;
    }
}

// ---------------- FC ----------------
__global__ void fc_kernel(const float* __restrict__ in, const float* __restrict__ W,
                          const float* __restrict__ bias, float* __restrict__ out,
                          int K, int N, int doRelu)
{
    int b = blockIdx.x;
    int g = threadIdx.x;
    extern __shared__ float xr[];
    for (int i = g; i < K; i += blockDim.x) xr[i] = in[(size_t)b * K + i];
    __syncthreads();
    if (g < N) {
        const float* wr = W + (size_t)g * K;
        float acc = bias[g];
        for (int k = 0; k < K; k++) acc = fmaf(wr[k], xr[k], acc);
        if (doRelu) acc = fmaxf(acc, 0.f);
        out[(size_t)b * N + g] = acc;
    }
}

extern "C" void kernel_launch(void* const* d_in, const int* in_sizes, int n_in,
                              void* d_out, int out_size, void* d_ws, size_t ws_size,
                              hipStream_t stream)
{
    (void)in_sizes; (void)n_in; (void)out_size;
    const float* x      = (const float*)d_in[0];
    const float* conv_w = (const float*)d_in[1];
    const float* conv_b = (const float*)d_in[2];
    const float* w_ih1  = (const float*)d_in[3];
    const float* w_hh1  = (const float*)d_in[4];
    const float* b1     = (const float*)d_in[5];
    const float* w_ih2  = (const float*)d_in[6];
    const float* w_hh2  = (const float*)d_in[7];
    const float* b2     = (const float*)d_in[8];
    const float* w_ih3  = (const float*)d_in[9];
    const float* w_hh3  = (const float*)d_in[10];
    const float* b3     = (const float*)d_in[11];
    const float* fc1_w  = (const float*)d_in[12];
    const float* fc1_b  = (const float*)d_in[13];
    const float* fc2_w  = (const float*)d_in[14];
    const float* fc2_b  = (const float*)d_in[15];
    const float* fc3_w  = (const float*)d_in[16];
    const float* fc3_b  = (const float*)d_in[17];
    const float* fc4_w  = (const float*)d_in[18];
    const float* fc4_b  = (const float*)d_in[19];
    float* out = (float*)d_out;
    char*  base = (char*)d_ws;

    const size_t MB = 1ull << 20;

    // footprint: 2 bf16 Y buffers + fp16 XW chunk + small
    auto need = [&](int s, int tc) -> size_t {
        size_t Bg = B_ALL / s;
        size_t YB = Bg * T_SZ * 256 * 2;                 // bf16 Y buffer
        size_t XW = (size_t)tc * Bg * 512 * 2 * 2;       // fp16 chunk, 2 dirs
        return 2 * YB + XW + 2 * MB;
    };

    int S = 8;
    for (int s : {1, 2, 4, 8}) {
        if (need(s, 16) <= ws_size) { S = s; break; }
    }
    int Tc = 16;
    while (Tc < 256 && need(S, Tc * 2) <= ws_size) Tc <<= 1;
    int lg = 0; while ((1 << lg) < Tc) lg++;
    int NC = T_SZ / Tc;

    int Bg = B_ALL / S;
    size_t YB = (size_t)Bg * T_SZ * 256 * 2;
    __hip_bfloat16* Y1 = (__hip_bfloat16*)base;
    __hip_bfloat16* Y2 = (__hip_bfloat16*)(base + YB);
    __hip_bfloat16* X1 = Y2;                             // aliased: X1 dead before Y2 written
    _Float16* XWc = (_Float16*)(base + 2 * YB);
    float* sm  = (float*)(base + 2 * YB + (size_t)Tc * Bg * 512 * 2 * 2);
    float* Hs = sm;                   // 2*Bg*128
    float* Cs = Hs + 2 * Bg * 128;
    float* H3 = Cs + 2 * Bg * 128;    // Bg*128
    float* F1 = H3 + Bg * 128;        // Bg*512
    float* F2 = F1 + Bg * 512;        // Bg*256
    float* F3 = F2 + Bg * 256;        // Bg*128

    int MT = Bg * Tc / 128;           // m-tiles per chunk

    for (int sp = 0; sp < S; ++sp) {
        int bg0 = sp * Bg;

        conv_relu_kernel<<<dim3(T_SZ / 4, Bg), 256, 0, stream>>>(x, conv_w, conv_b, X1, bg0);

        // layer 1 (D=64, H=128) : X1 -> Y1
        for (int ci = 0; ci < NC; ++ci) {
            proj_mfma<<<dim3(MT, 4, 2), 256, 0, stream>>>(
                X1, w_ih1, b1, XWc, 64, 512, lg, ci * Tc, Bg);
            lstm_rec_mfma<128, 8, true><<<dim3(Bg / 16, 2), 512, 0, stream>>>(
                XWc, w_hh1, Y1, nullptr, Hs, Cs, Bg, Tc, ci * Tc, ci == 0, 0);
        }
        // layer 2 (D=256, H=128) : Y1 -> Y2
        for (int ci = 0; ci < NC; ++ci) {
            proj_mfma<<<dim3(MT, 4, 2), 256, 0, stream>>>(
                Y1, w_ih2, b2, XWc, 256, 512, lg, ci * Tc, Bg);
            lstm_rec_mfma<128, 8, true><<<dim3(Bg / 16, 2), 512, 0, stream>>>(
                XWc, w_hh2, Y2, nullptr, Hs, Cs, Bg, Tc, ci * Tc, ci == 0, 0);
        }
        // layer 3 (D=256, H=64): forward full scan (final h only) + backward single step
        for (int ci = 0; ci < NC; ++ci) {
            proj_mfma<<<dim3(MT, 2, 1), 256, 0, stream>>>(
                Y2, w_ih3, b3, XWc, 256, 256, lg, ci * Tc, Bg);
            lstm_rec_mfma<64, 4, false><<<dim3(Bg / 16, 1), 256, 0, stream>>>(
                XWc, w_hh3, nullptr, H3, Hs, Cs, Bg, Tc, ci * Tc, ci == 0, ci == NC - 1);
        }
        lstm3_bwd_kernel<<<Bg, 256, 0, stream>>>(Y2, w_ih3, b3, H3);

        fc_kernel<<<Bg, 512, 128 * 4, stream>>>(H3, fc1_w, fc1_b, F1, 128, 512, 1);
        fc_kernel<<<Bg, 256, 512 * 4, stream>>>(F1, fc2_w, fc2_b, F2, 512, 256, 1);
        fc_kernel<<<Bg, 128, 256 * 4, stream>>>(F2, fc3_w, fc3_b, F3, 256, 128, 1);
        fc_kernel<<<Bg, 64, 128 * 4, stream>>>(F3, fc4_w, fc4_b, out + (size_t)bg0 * 2, 128, 2, 0);
    }
}

// Round 7
// 8643.098 us; speedup vs baseline: 1.4610x; 1.0805x over previous
//
#include <hip/hip_runtime.h>
#include <hip/hip_bf16.h>
#include <cstdint>
#include <cstddef>

#define B_ALL 256
#define T_SZ  1024

typedef __attribute__((ext_vector_type(8))) __bf16    bf16x8;
typedef __attribute__((ext_vector_type(4))) __bf16    bf16x4;
typedef __attribute__((ext_vector_type(4))) float     f32x4;
typedef __attribute__((ext_vector_type(4))) _Float16  halfx4;

__device__ __forceinline__ float sig_(float x) {
    return __builtin_amdgcn_rcpf(1.0f + __expf(-x));
}
__device__ __forceinline__ float tanh_(float x) {
    float ax = fabsf(x);
    float e  = __expf(-2.0f * ax);
    float t  = (1.0f - e) * __builtin_amdgcn_rcpf(1.0f + e);
    return copysignf(t, x);
}

// ---------------- conv (causal, k=5) + relu -> X1[b_local][t][64] (bf16) ----------------
__global__ void conv_relu_kernel(const float* __restrict__ x, const float* __restrict__ w,
                                 const float* __restrict__ bias, __hip_bfloat16* __restrict__ out,
                                 int bg0)
{
    int c  = threadIdx.x & 63;
    int tq = threadIdx.x >> 6;
    int t  = blockIdx.x * 4 + tq;
    int b  = blockIdx.y;
    const float* xb = x + (size_t)(bg0 + b) * T_SZ;
    float s = bias[c];
#pragma unroll
    for (int k = 0; k < 5; ++k) {
        int ti = t - 4 + k;
        float xv = (ti >= 0) ? xb[ti] : 0.0f;
        s = fmaf(w[c * 5 + k], xv, s);
    }
    out[((size_t)b * T_SZ + t) * 64 + c] = __float2bfloat16(fmaxf(s, 0.0f));
}

// ---------------- fused: LSTM rec (chunk ci) + input-proj MFMA (chunk ci+1) ----------------
// Blocks [0, nRecBlocks): recurrence, 4 batch rows/block (tile rows {0,4,8,12} -> each
// lane exactly 1 h-unit, no divergence). Blocks [nRecBlocks, ...): proj GEMM 128x128
// tile, 8 waves (2m x 4n of 64x32), writes fp16 gate-interleaved XW of the NEXT chunk
// into the other parity buffer. No intra-launch dependency between roles.
template <int H, int NW, bool WRITE_Y>
__global__ __launch_bounds__(512, 1) void fused_step(
    // rec
    const _Float16* __restrict__ xwR, const float* __restrict__ w_hh,
    __hip_bfloat16* __restrict__ y, float* __restrict__ lastOut,
    float* __restrict__ Hst, float* __restrict__ Cst,
    int Bg, int Tc, int lg, int step0, int zeroInit, int writeLast,
    int nRecBlocks, int ndirRec,
    // proj
    const __hip_bfloat16* __restrict__ A, const float* __restrict__ W,
    const float* __restrict__ bias, _Float16* __restrict__ xwOut,
    int K, int N, int t0p, int MT, int NT)
{
    __shared__ __align__(16) char smem[20608];
    const int tid = threadIdx.x;
    const int w   = tid >> 6;
    const int l   = tid & 63;
    const int l15 = l & 15;
    const int q4  = l >> 4;

    if ((int)blockIdx.x < nRecBlocks) {
        // ================= REC =================
        constexpr int FH = 4 * H;
        constexpr int KT = H / 32;
        constexpr int LW = H + 8;
        int rb  = blockIdx.x;
        int dir = (ndirRec == 2) ? (rb & 1) : 0;
        int bt  = (ndirRec == 2) ? (rb >> 1) : rb;
        int brow = bt * 4 + q4;               // this lane's batch row
        int hh   = w * 16 + l15;

        __bf16* hb = (__bf16*)smem;           // [parity][hi/lo][16][LW]
        auto HA = [&](int p, int hl, int m) -> __bf16* {
            return hb + ((size_t)((p * 2 + hl) * 16 + m)) * LW;
        };
        for (int i = tid; i < 4 * 16 * LW; i += 512) hb[i] = (__bf16)0.f;

        bf16x8 wf[4][KT];
        float creg = 0.f;
        const _Float16* xb = xwR;
        if (w < NW) {
            const float* wbase = w_hh + (size_t)dir * FH * H;
#pragma unroll
            for (int gate = 0; gate < 4; ++gate) {
                const float* wrow = wbase + (size_t)(gate * H + hh) * H;
#pragma unroll
                for (int kt = 0; kt < KT; ++kt) {
                    const float* src = wrow + kt * 32 + q4 * 8;
                    float4 a = *(const float4*)(src);
                    float4 b = *(const float4*)(src + 4);
                    bf16x8 v;
                    v[0] = (__bf16)a.x; v[1] = (__bf16)a.y; v[2] = (__bf16)a.z; v[3] = (__bf16)a.w;
                    v[4] = (__bf16)b.x; v[5] = (__bf16)b.y; v[6] = (__bf16)b.z; v[7] = (__bf16)b.w;
                    wf[gate][kt] = v;
                }
            }
            float hv = 0.f;
            if (!zeroInit) {
                hv   = Hst[((size_t)dir * Bg + brow) * H + hh];
                creg = Cst[((size_t)dir * Bg + brow) * H + hh];
            }
            __bf16 hi = (__bf16)hv;
            HA(0, 0, q4 * 4)[hh] = hi;
            HA(0, 1, q4 * 4)[hh] = (__bf16)(hv - (float)hi);
        }
        xb = xwR + (size_t)dir * Tc * Bg * FH + (size_t)brow * FH + hh * 4;
        const size_t xstride = (size_t)Bg * FH;

        halfx4 pf[2];
        if (w < NW) {
            pf[0] = *(const halfx4*)xb;
            pf[1] = *(const halfx4*)(xb + xstride);
        }
        __syncthreads();

        for (int sl = 0; sl < Tc; ++sl) {
            const int p = sl & 1;
            const int t = dir ? (T_SZ - 1 - (step0 + sl)) : (step0 + sl);
            if (w < NW) {
                bf16x8 ahi[KT], alo[KT];
#pragma unroll
                for (int kt = 0; kt < KT; ++kt) {
                    ahi[kt] = *(const bf16x8*)&HA(p, 0, l15)[kt * 32 + q4 * 8];
                    alo[kt] = *(const bf16x8*)&HA(p, 1, l15)[kt * 32 + q4 * 8];
                }
                halfx4 xv = pf[p];
                if (sl + 2 < Tc) pf[p] = *(const halfx4*)(xb + (size_t)(sl + 2) * xstride);

                float g4[4];
#pragma unroll
                for (int gate = 0; gate < 4; ++gate) {
                    f32x4 ah = {0.f, 0.f, 0.f, 0.f};
                    f32x4 al = {0.f, 0.f, 0.f, 0.f};
#pragma unroll
                    for (int kt = 0; kt < KT; ++kt)
                        ah = __builtin_amdgcn_mfma_f32_16x16x32_bf16(ahi[kt], wf[gate][kt], ah, 0, 0, 0);
#pragma unroll
                    for (int kt = 0; kt < KT; ++kt)
                        al = __builtin_amdgcn_mfma_f32_16x16x32_bf16(alo[kt], wf[gate][kt], al, 0, 0, 0);
                    g4[gate] = ah[0] + al[0] + (float)xv[gate];
                }
                float iv = fminf(fmaxf(g4[0], -25.f), 25.f);
                float fv = fminf(fmaxf(g4[1], -25.f), 25.f);
                float gv = fminf(fmaxf(g4[2], -12.f), 12.f);
                float ov = fminf(fmaxf(g4[3], -25.f), 25.f);
                float Af = 1.f + __expf(-fv);
                float Bi = 1.f + __expf(-iv);
                float G  = __expf(2.f * gv);
                float Gp = G + 1.f, Gm = G - 1.f;
                float num = fmaf(creg * Bi, Gp, Af * Gm);
                float cn  = num * __builtin_amdgcn_rcpf(Af * Bi * Gp);
                creg = cn;
                float cc = fminf(fmaxf(cn, -25.f), 25.f);
                float E  = __expf(2.f * cc);
                float hv = (E - 1.f) * __builtin_amdgcn_rcpf((1.f + __expf(-ov)) * (E + 1.f));
                __bf16 hi = (__bf16)hv;
                HA(1 - p, 0, q4 * 4)[hh] = hi;
                HA(1 - p, 1, q4 * 4)[hh] = (__bf16)(hv - (float)hi);
                if (WRITE_Y) {
                    y[((size_t)brow * T_SZ + t) * (2 * H) + dir * H + hh] = __float2bfloat16(hv);
                } else if (writeLast && sl == Tc - 1) {
                    lastOut[brow * 128 + hh] = hv;
                }
                if (sl == Tc - 1) {
                    Hst[((size_t)dir * Bg + brow) * H + hh] = hv;
                    Cst[((size_t)dir * Bg + brow) * H + hh] = cn;
                }
            }
            __syncthreads();
        }
    } else {
        // ================= PROJ =================
        const int Tcp = 1 << lg;
        const int H4  = N >> 2;
        int pb   = blockIdx.x - nRecBlocks;
        int mi   = pb % MT;
        int rest = pb / MT;
        int ni   = rest % NT;
        int dir  = rest / NT;
        const float* Wd = W + (size_t)dir * N * K;
        const float* bd = bias + (size_t)dir * N;
        _Float16*    od = xwOut + (size_t)dir * Tcp * Bg * N;

        __bf16 (*As)[40] = (__bf16(*)[40])smem;             // 128*40*2 = 10240
        __bf16 (*Ws)[40] = (__bf16(*)[40])(smem + 10240);   // 10240

        const int m0 = mi * 128;
        const int n0 = ni * 128;
        const int wm = (w & 1) * 64;
        const int wn = (w >> 1) * 32;

        f32x4 acc[4][2];
#pragma unroll
        for (int i = 0; i < 4; i++)
#pragma unroll
            for (int j = 0; j < 2; j++) acc[i][j] = (f32x4){0.f, 0.f, 0.f, 0.f};

        for (int k0 = 0; k0 < K; k0 += 32) {
            {   // stage A: 128 rows x 32 bf16, one pass of 512 x 16B
                int row = tid >> 2;
                int ko  = (tid & 3) * 8;
                int m   = m0 + row;
                int bA  = m >> lg, tl = m & (Tcp - 1);
                int t   = dir ? (T_SZ - 1 - (t0p + tl)) : (t0p + tl);
                const __hip_bfloat16* src = A + ((size_t)bA * T_SZ + t) * K + k0 + ko;
                *(bf16x8*)&As[row][ko] = *(const bf16x8*)src;
            }
#pragma unroll
            for (int pass = 0; pass < 2; ++pass) {  // stage W: 128 rows x 32 f32->bf16
                int c2  = tid + pass * 512;
                int row = c2 >> 3;
                int ko  = (c2 & 7) * 4;
                int n_o = n0 + row;
                int nr  = (n_o & 3) * H4 + (n_o >> 2);
                float4 f = *(const float4*)&Wd[(size_t)nr * K + k0 + ko];
                bf16x4 v;
                v[0] = (__bf16)f.x; v[1] = (__bf16)f.y; v[2] = (__bf16)f.z; v[3] = (__bf16)f.w;
                *(bf16x4*)&Ws[row][ko] = v;
            }
            __syncthreads();
            bf16x8 af[4], bfr[2];
#pragma unroll
            for (int i = 0; i < 4; i++) af[i]  = *(const bf16x8*)&As[wm + i * 16 + l15][q4 * 8];
#pragma unroll
            for (int j = 0; j < 2; j++) bfr[j] = *(const bf16x8*)&Ws[wn + j * 16 + l15][q4 * 8];
#pragma unroll
            for (int i = 0; i < 4; i++)
#pragma unroll
                for (int j = 0; j < 2; j++)
                    acc[i][j] = __builtin_amdgcn_mfma_f32_16x16x32_bf16(af[i], bfr[j], acc[i][j], 0, 0, 0);
            __syncthreads();
        }
#pragma unroll
        for (int i = 0; i < 4; i++) {
#pragma unroll
            for (int j = 0; j < 2; j++) {
                int n_o = n0 + wn + j * 16 + l15;
                float bi = bd[(n_o & 3) * H4 + (n_o >> 2)];
#pragma unroll
                for (int r = 0; r < 4; r++) {
                    int m  = m0 + wm + i * 16 + q4 * 4 + r;
                    int bO = m >> lg, tl = m & (Tcp - 1);
                    od[((size_t)tl * Bg + bO) * N + n_o] = (_Float16)(acc[i][j][r] + bi);
                }
            }
        }
    }
}

// ---------------- layer-3 backward: exactly one step from zero state ----------------
__global__ __launch_bounds__(256) void lstm3_bwd_kernel(
    const __hip_bfloat16* __restrict__ y2, const float* __restrict__ w_ih3,
    const float* __restrict__ b3, float* __restrict__ H3)
{
    int b = blockIdx.x, g = threadIdx.x;
    __shared__ float xr[256];
    __shared__ float gsh[256];
    xr[g] = __bfloat162float(y2[((size_t)b * T_SZ + (T_SZ - 1)) * 256 + g]);
    __syncthreads();
    const float* wr = w_ih3 + (size_t)256 * 256 + (size_t)g * 256;  // dir 1
    float acc = b3[256 + g];
#pragma unroll 4
    for (int k = 0; k < 256; k++) acc = fmaf(wr[k], xr[k], acc);
    gsh[g] = acc;
    __syncthreads();
    if (g < 64) {
        float iv = gsh[g], gv = gsh[128 + g], ov = gsh[192 + g];
        float ct = sig_(iv) * tanh_(gv);   // c0 = 0 -> forget term vanishes
        float hv = sig_(ov) * tanh_(ct);
        H3[b * 128 + 64 + g] = hv;
    }
}

// ---------------- FC ----------------
__global__ void fc_kernel(const float* __restrict__ in, const float* __restrict__ W,
                          const float* __restrict__ bias, float* __restrict__ out,
                          int K, int N, int doRelu)
{
    int b = blockIdx.x;
    int g = threadIdx.x;
    extern __shared__ float xr[];
    for (int i = g; i < K; i += blockDim.x) xr[i] = in[(size_t)b * K + i];
    __syncthreads();
    if (g < N) {
        const float* wr = W + (size_t)g * K;
        float acc = bias[g];
        for (int k = 0; k < K; k++) acc = fmaf(wr[k], xr[k], acc);
        if (doRelu) acc = fmaxf(acc, 0.f);
        out[(size_t)b * N + g] = acc;
    }
}

extern "C" void kernel_launch(void* const* d_in, const int* in_sizes, int n_in,
                              void* d_out, int out_size, void* d_ws, size_t ws_size,
                              hipStream_t stream)
{
    (void)in_sizes; (void)n_in; (void)out_size;
    const float* x      = (const float*)d_in[0];
    const float* conv_w = (const float*)d_in[1];
    const float* conv_b = (const float*)d_in[2];
    const float* w_ih1  = (const float*)d_in[3];
    const float* w_hh1  = (const float*)d_in[4];
    const float* b1     = (const float*)d_in[5];
    const float* w_ih2  = (const float*)d_in[6];
    const float* w_hh2  = (const float*)d_in[7];
    const float* b2     = (const float*)d_in[8];
    const float* w_ih3  = (const float*)d_in[9];
    const float* w_hh3  = (const float*)d_in[10];
    const float* b3     = (const float*)d_in[11];
    const float* fc1_w  = (const float*)d_in[12];
    const float* fc1_b  = (const float*)d_in[13];
    const float* fc2_w  = (const float*)d_in[14];
    const float* fc2_b  = (const float*)d_in[15];
    const float* fc3_w  = (const float*)d_in[16];
    const float* fc3_b  = (const float*)d_in[17];
    const float* fc4_w  = (const float*)d_in[18];
    const float* fc4_b  = (const float*)d_in[19];
    float* out = (float*)d_out;
    char*  base = (char*)d_ws;

    const size_t MB = 1ull << 20;

    // footprint: 2 bf16 Y buffers + 2 fp16 XW chunk buffers (double-buffered) + small
    auto need = [&](int s, int tc) -> size_t {
        size_t Bg = B_ALL / s;
        size_t YB = Bg * T_SZ * 256 * 2;
        size_t XW = (size_t)tc * Bg * 512 * 2 * 2;       // fp16, 2 dirs
        return 2 * YB + 2 * XW + 2 * MB;
    };

    int S = 8;
    for (int s : {1, 2, 4, 8}) {
        if (need(s, 32) <= ws_size) { S = s; break; }
    }
    int Tc = 32;
    while (Tc < 256 && need(S, Tc * 2) <= ws_size) Tc <<= 1;
    int lg = 0; while ((1 << lg) < Tc) lg++;
    int NC = T_SZ / Tc;

    int Bg = B_ALL / S;
    size_t YB  = (size_t)Bg * T_SZ * 256 * 2;
    size_t XWB = (size_t)Tc * Bg * 512 * 2 * 2;
    __hip_bfloat16* Y1 = (__hip_bfloat16*)base;
    __hip_bfloat16* Y2 = (__hip_bfloat16*)(base + YB);
    __hip_bfloat16* X1 = Y2;                             // aliased: X1 dead before Y2 written
    _Float16* XW[2] = { (_Float16*)(base + 2 * YB), (_Float16*)(base + 2 * YB + XWB) };
    float* sm  = (float*)(base + 2 * YB + 2 * XWB);
    float* Hs = sm;                   // 2*Bg*128
    float* Cs = Hs + 2 * Bg * 128;
    float* H3 = Cs + 2 * Bg * 128;    // Bg*128
    float* F1 = H3 + Bg * 128;        // Bg*512
    float* F2 = F1 + Bg * 512;        // Bg*256
    float* F3 = F2 + Bg * 256;        // Bg*128

    int MT = Bg * Tc / 128;

    for (int sp = 0; sp < S; ++sp) {
        int bg0 = sp * Bg;

        conv_relu_kernel<<<dim3(T_SZ / 4, Bg), 256, 0, stream>>>(x, conv_w, conv_b, X1, bg0);

        // ---- layer 1 (K=64, N=512, H=128, 2 dirs): X1 -> Y1 ----
        {
            int NT = 4, ndir = 2, Kl = 64, Nn = 512;
            int nProj = MT * NT * ndir, nRec = (Bg / 4) * ndir;
            fused_step<128, 8, true><<<nProj, 512, 0, stream>>>(
                XW[0], w_hh1, Y1, H3, Hs, Cs, Bg, Tc, lg, 0, 1, 0, 0, ndir,
                X1, w_ih1, b1, XW[0], Kl, Nn, 0, MT, NT);
            int par = 0;
            for (int ci = 0; ci < NC; ++ci) {
                int last = (ci == NC - 1);
                int grid = nRec + (last ? 0 : nProj);
                fused_step<128, 8, true><<<grid, 512, 0, stream>>>(
                    XW[par], w_hh1, Y1, H3, Hs, Cs, Bg, Tc, lg, ci * Tc, ci == 0, 0, nRec, ndir,
                    X1, w_ih1, b1, XW[1 - par], Kl, Nn, (ci + 1) * Tc, MT, NT);
                par ^= 1;
            }
        }
        // ---- layer 2 (K=256, N=512, H=128, 2 dirs): Y1 -> Y2 ----
        {
            int NT = 4, ndir = 2, Kl = 256, Nn = 512;
            int nProj = MT * NT * ndir, nRec = (Bg / 4) * ndir;
            fused_step<128, 8, true><<<nProj, 512, 0, stream>>>(
                XW[0], w_hh2, Y2, H3, Hs, Cs, Bg, Tc, lg, 0, 1, 0, 0, ndir,
                Y1, w_ih2, b2, XW[0], Kl, Nn, 0, MT, NT);
            int par = 0;
            for (int ci = 0; ci < NC; ++ci) {
                int last = (ci == NC - 1);
                int grid = nRec + (last ? 0 : nProj);
                fused_step<128, 8, true><<<grid, 512, 0, stream>>>(
                    XW[par], w_hh2, Y2, H3, Hs, Cs, Bg, Tc, lg, ci * Tc, ci == 0, 0, nRec, ndir,
                    Y1, w_ih2, b2, XW[1 - par], Kl, Nn, (ci + 1) * Tc, MT, NT);
                par ^= 1;
            }
        }
        // ---- layer 3 fwd (K=256, N=256, H=64, 1 dir): Y2 -> H3[:,0:64] ----
        {
            int NT = 2, ndir = 1, Kl = 256, Nn = 256;
            int nProj = MT * NT * ndir, nRec = (Bg / 4) * ndir;
            fused_step<64, 4, false><<<nProj, 512, 0, stream>>>(
                XW[0], w_hh3, nullptr, H3, Hs, Cs, Bg, Tc, lg, 0, 1, 0, 0, ndir,
                Y2, w_ih3, b3, XW[0], Kl, Nn, 0, MT, NT);
            int par = 0;
            for (int ci = 0; ci < NC; ++ci) {
                int last = (ci == NC - 1);
                int grid = nRec + (last ? 0 : nProj);
                fused_step<64, 4, false><<<grid, 512, 0, stream>>>(
                    XW[par], w_hh3, nullptr, H3, Hs, Cs, Bg, Tc, lg, ci * Tc, ci == 0, last, nRec, ndir,
                    Y2, w_ih3, b3, XW[1 - par], Kl, Nn, (ci + 1) * Tc, MT, NT);
                par ^= 1;
            }
        }
        lstm3_bwd_kernel<<<Bg, 256, 0, stream>>>(Y2, w_ih3, b3, H3);

        fc_kernel<<<Bg, 512, 128 * 4, stream>>>(H3, fc1_w, fc1_b, F1, 128, 512, 1);
        fc_kernel<<<Bg, 256, 512 * 4, stream>>>(F1, fc2_w, fc2_b, F2, 512, 256, 1);
        fc_kernel<<<Bg, 128, 256 * 4, stream>>>(F2, fc3_w, fc3_b, F3, 256, 128, 1);
        fc_kernel<<<Bg, 64, 128 * 4, stream>>>(F3, fc4_w, fc4_b, out + (size_t)bg0 * 2, 128, 2, 0);
    }
}

// Round 8
// 8206.110 us; speedup vs baseline: 1.5388x; 1.0533x over previous
//
#include <hip/hip_runtime.h>
#include <hip/hip_bf16.h>
#include <cstdint>
#include <cstddef>

#define B_ALL 256
#define T_SZ  1024

typedef __attribute__((ext_vector_type(8))) _Float16  halfx8;
typedef __attribute__((ext_vector_type(4))) _Float16  halfx4;
typedef __attribute__((ext_vector_type(4))) float     f32x4;

__device__ __forceinline__ float sig_(float x) {
    return __builtin_amdgcn_rcpf(1.0f + __expf(-x));
}
__device__ __forceinline__ float tanh_(float x) {
    float ax = fabsf(x);
    float e  = __expf(-2.0f * ax);
    float t  = (1.0f - e) * __builtin_amdgcn_rcpf(1.0f + e);
    return copysignf(t, x);
}

// ---------------- conv (causal, k=5) + relu -> X1[b_local][t][64] (fp16) ----------------
__global__ void conv_relu_kernel(const float* __restrict__ x, const float* __restrict__ w,
                                 const float* __restrict__ bias, _Float16* __restrict__ out,
                                 int bg0)
{
    int c  = threadIdx.x & 63;
    int tq = threadIdx.x >> 6;
    int t  = blockIdx.x * 4 + tq;
    int b  = blockIdx.y;
    const float* xb = x + (size_t)(bg0 + b) * T_SZ;
    float s = bias[c];
#pragma unroll
    for (int k = 0; k < 5; ++k) {
        int ti = t - 4 + k;
        float xv = (ti >= 0) ? xb[ti] : 0.0f;
        s = fmaf(w[c * 5 + k], xv, s);
    }
    out[((size_t)b * T_SZ + t) * 64 + c] = (_Float16)fmaxf(s, 0.0f);
}

// ---------------- fused: LSTM rec (chunk ci) + input-proj MFMA (chunk ci+1) ----------------
// Blocks [0, nRecBlocks): recurrence, 4 batch rows/block. Blocks beyond: proj GEMM
// 128x128 tile (8 waves = 2m x 4n of 64x32), fp16 MFMA, LDS-transposed coalesced
// epilogue, writes fp16 gate-interleaved XW of the NEXT chunk (other parity buffer).
template <int H, int NW, bool WRITE_Y>
__global__ __launch_bounds__(512, 1) void fused_step(
    // rec
    const _Float16* __restrict__ xwR, const float* __restrict__ w_hh,
    _Float16* __restrict__ y, float* __restrict__ lastOut,
    float* __restrict__ Hst, float* __restrict__ Cst,
    int Bg, int Tc, int lg, int step0, int zeroInit, int writeLast,
    int nRecBlocks, int ndirRec,
    // proj
    const _Float16* __restrict__ A, const float* __restrict__ W,
    const float* __restrict__ bias, _Float16* __restrict__ xwOut,
    int K, int N, int t0p, int MT, int NT)
{
    __shared__ __align__(16) char smem[32768];
    const int tid = threadIdx.x;
    const int w   = tid >> 6;
    const int l   = tid & 63;
    const int l15 = l & 15;
    const int q4  = l >> 4;

    if ((int)blockIdx.x < nRecBlocks) {
        // ================= REC =================
        constexpr int FH = 4 * H;
        constexpr int KT = H / 32;
        constexpr int LW = H + 8;
        int rb  = blockIdx.x;
        int dir = (ndirRec == 2) ? (rb & 1) : 0;
        int bt  = (ndirRec == 2) ? (rb >> 1) : rb;
        int brow = bt * 4 + q4;               // this lane's batch row
        int hh   = w * 16 + l15;

        _Float16* hb = (_Float16*)smem;       // [parity][16][LW]
        auto HA = [&](int p, int m) -> _Float16* {
            return hb + ((size_t)(p * 16 + m)) * LW;
        };
        for (int i = tid; i < 2 * 16 * LW; i += 512) hb[i] = (_Float16)0.f;

        halfx8 wf[4][KT];
        float creg = 0.f;
        if (w < NW) {
            const float* wbase = w_hh + (size_t)dir * FH * H;
#pragma unroll
            for (int gate = 0; gate < 4; ++gate) {
                const float* wrow = wbase + (size_t)(gate * H + hh) * H;
#pragma unroll
                for (int kt = 0; kt < KT; ++kt) {
                    const float* src = wrow + kt * 32 + q4 * 8;
                    float4 a = *(const float4*)(src);
                    float4 b = *(const float4*)(src + 4);
                    halfx8 v;
                    v[0] = (_Float16)a.x; v[1] = (_Float16)a.y; v[2] = (_Float16)a.z; v[3] = (_Float16)a.w;
                    v[4] = (_Float16)b.x; v[5] = (_Float16)b.y; v[6] = (_Float16)b.z; v[7] = (_Float16)b.w;
                    wf[gate][kt] = v;
                }
            }
            float hv = 0.f;
            if (!zeroInit) {
                hv   = Hst[((size_t)dir * Bg + brow) * H + hh];
                creg = Cst[((size_t)dir * Bg + brow) * H + hh];
            }
            HA(0, q4 * 4)[hh] = (_Float16)hv;
        }
        const _Float16* xb = xwR + (size_t)dir * Tc * Bg * FH + (size_t)brow * FH + hh * 4;
        const size_t xstride = (size_t)Bg * FH;

        halfx4 pf[2];
        if (w < NW) {
            pf[0] = *(const halfx4*)xb;
            pf[1] = *(const halfx4*)(xb + xstride);
        }
        __syncthreads();

        for (int sl = 0; sl < Tc; ++sl) {
            const int p = sl & 1;
            const int t = dir ? (T_SZ - 1 - (step0 + sl)) : (step0 + sl);
            if (w < NW) {
                halfx8 af[KT];
#pragma unroll
                for (int kt = 0; kt < KT; ++kt)
                    af[kt] = *(const halfx8*)&HA(p, l15)[kt * 32 + q4 * 8];
                halfx4 xv = pf[p];
                if (sl + 2 < Tc) pf[p] = *(const halfx4*)(xb + (size_t)(sl + 2) * xstride);

                float g4[4];
#pragma unroll
                for (int gate = 0; gate < 4; ++gate) {
                    f32x4 a = {0.f, 0.f, 0.f, 0.f};
#pragma unroll
                    for (int kt = 0; kt < KT; ++kt)
                        a = __builtin_amdgcn_mfma_f32_16x16x32_f16(af[kt], wf[gate][kt], a, 0, 0, 0);
                    g4[gate] = a[0] + (float)xv[gate];
                }
                float iv = fminf(fmaxf(g4[0], -25.f), 25.f);
                float fv = fminf(fmaxf(g4[1], -25.f), 25.f);
                float gv = fminf(fmaxf(g4[2], -12.f), 12.f);
                float ov = fminf(fmaxf(g4[3], -25.f), 25.f);
                float Af = 1.f + __expf(-fv);
                float Bi = 1.f + __expf(-iv);
                float G  = __expf(2.f * gv);
                float Gp = G + 1.f, Gm = G - 1.f;
                float num = fmaf(creg * Bi, Gp, Af * Gm);
                float cn  = num * __builtin_amdgcn_rcpf(Af * Bi * Gp);
                creg = cn;
                float cc = fminf(fmaxf(cn, -25.f), 25.f);
                float E  = __expf(2.f * cc);
                float hv = (E - 1.f) * __builtin_amdgcn_rcpf((1.f + __expf(-ov)) * (E + 1.f));
                HA(1 - p, q4 * 4)[hh] = (_Float16)hv;
                if (WRITE_Y) {
                    y[((size_t)brow * T_SZ + t) * (2 * H) + dir * H + hh] = (_Float16)hv;
                } else if (writeLast && sl == Tc - 1) {
                    lastOut[brow * 128 + hh] = hv;
                }
                if (sl == Tc - 1) {
                    Hst[((size_t)dir * Bg + brow) * H + hh] = hv;
                    Cst[((size_t)dir * Bg + brow) * H + hh] = cn;
                }
            }
            __syncthreads();
        }
    } else {
        // ================= PROJ =================
        const int Tcp = 1 << lg;
        const int H4  = N >> 2;
        int pb   = blockIdx.x - nRecBlocks;
        int mi   = pb % MT;
        int rest = pb / MT;
        int ni   = rest % NT;
        int dir  = rest / NT;
        const float* Wd = W + (size_t)dir * N * K;
        const float* bd = bias + (size_t)dir * N;
        _Float16*    od = xwOut + (size_t)dir * Tcp * Bg * N;

        _Float16 (*As)[40] = (_Float16(*)[40])smem;             // 128*40*2 = 10240
        _Float16 (*Ws)[40] = (_Float16(*)[40])(smem + 10240);   // 10240

        const int m0 = mi * 128;
        const int n0 = ni * 128;
        const int wm = (w & 1) * 64;
        const int wn = (w >> 1) * 32;

        f32x4 acc[4][2];
#pragma unroll
        for (int i = 0; i < 4; i++)
#pragma unroll
            for (int j = 0; j < 2; j++) acc[i][j] = (f32x4){0.f, 0.f, 0.f, 0.f};

        for (int k0 = 0; k0 < K; k0 += 32) {
            {   // stage A: 128 rows x 32 fp16, one pass of 512 x 16B
                int row = tid >> 2;
                int ko  = (tid & 3) * 8;
                int m   = m0 + row;
                int bA  = m >> lg, tl = m & (Tcp - 1);
                int t   = dir ? (T_SZ - 1 - (t0p + tl)) : (t0p + tl);
                const _Float16* src = A + ((size_t)bA * T_SZ + t) * K + k0 + ko;
                *(halfx8*)&As[row][ko] = *(const halfx8*)src;
            }
#pragma unroll
            for (int pass = 0; pass < 2; ++pass) {  // stage W: 128 rows x 32 f32->f16
                int c2  = tid + pass * 512;
                int row = c2 >> 3;
                int ko  = (c2 & 7) * 4;
                int n_o = n0 + row;
                int nr  = (n_o & 3) * H4 + (n_o >> 2);
                float4 f = *(const float4*)&Wd[(size_t)nr * K + k0 + ko];
                halfx4 v;
                v[0] = (_Float16)f.x; v[1] = (_Float16)f.y; v[2] = (_Float16)f.z; v[3] = (_Float16)f.w;
                *(halfx4*)&Ws[row][ko] = v;
            }
            __syncthreads();
            halfx8 af[4], bfr[2];
#pragma unroll
            for (int i = 0; i < 4; i++) af[i]  = *(const halfx8*)&As[wm + i * 16 + l15][q4 * 8];
#pragma unroll
            for (int j = 0; j < 2; j++) bfr[j] = *(const halfx8*)&Ws[wn + j * 16 + l15][q4 * 8];
#pragma unroll
            for (int i = 0; i < 4; i++)
#pragma unroll
                for (int j = 0; j < 2; j++)
                    acc[i][j] = __builtin_amdgcn_mfma_f32_16x16x32_f16(af[i], bfr[j], acc[i][j], 0, 0, 0);
            __syncthreads();
        }

        // epilogue: stage C in LDS [128][128] fp16, then coalesced 16B stores
        _Float16 (*Cs)[128] = (_Float16(*)[128])smem;
#pragma unroll
        for (int i = 0; i < 4; i++) {
#pragma unroll
            for (int j = 0; j < 2; j++) {
                int o_l = wn + j * 16 + l15;
                int n_o = n0 + o_l;
                float bi = bd[(n_o & 3) * H4 + (n_o >> 2)];
#pragma unroll
                for (int r = 0; r < 4; r++)
                    Cs[wm + i * 16 + q4 * 4 + r][o_l] = (_Float16)(acc[i][j][r] + bi);
            }
        }
        __syncthreads();
        {
            int row = tid >> 2;          // 0..127
            int seg = tid & 3;           // 0..3, 32 fp16 each
            int m   = m0 + row;
            int bO  = m >> lg, tl = m & (Tcp - 1);
            _Float16* dst = od + ((size_t)tl * Bg + bO) * N + n0 + seg * 32;
            const _Float16* srcp = &Cs[row][seg * 32];
#pragma unroll
            for (int u = 0; u < 4; ++u)
                *(halfx8*)(dst + u * 8) = *(const halfx8*)(srcp + u * 8);
        }
    }
}

// ---------------- layer-3 backward: exactly one step from zero state ----------------
__global__ __launch_bounds__(256) void lstm3_bwd_kernel(
    const _Float16* __restrict__ y2, const float* __restrict__ w_ih3,
    const float* __restrict__ b3, float* __restrict__ H3)
{
    int b = blockIdx.x, g = threadIdx.x;
    __shared__ float xr[256];
    __shared__ float gsh[256];
    xr[g] = (float)y2[((size_t)b * T_SZ + (T_SZ - 1)) * 256 + g];
    __syncthreads();
    const float* wr = w_ih3 + (size_t)256 * 256 + (size_t)g * 256;  // dir 1
    float acc = b3[256 + g];
#pragma unroll 4
    for (int k = 0; k < 256; k++) acc = fmaf(wr[k], xr[k], acc);
    gsh[g] = acc;
    __syncthreads();
    if (g < 64) {
        float iv = gsh[g], gv = gsh[128 + g], ov = gsh[192 + g];
        float ct = sig_(iv) * tanh_(gv);   // c0 = 0 -> forget term vanishes
        float hv = sig_(ov) * tanh_(ct);
        H3[b * 128 + 64 + g] = hv;
    }
}

// ---------------- FC ----------------
__global__ void fc_kernel(const float* __restrict__ in, const float* __restrict__ W,
                          const float* __restrict__ bias, float* __restrict__ out,
                          int K, int N, int doRelu)
{
    int b = blockIdx.x;
    int g = threadIdx.x;
    extern __shared__ float xr[];
    for (int i = g; i < K; i += blockDim.x) xr[i] = in[(size_t)b * K + i];
    __syncthreads();
    if (g < N) {
        const float* wr = W + (size_t)g * K;
        float acc = bias[g];
        for (int k = 0; k < K; k++) acc = fmaf(wr[k], xr[k], acc);
        if (doRelu) acc = fmaxf(acc, 0.f);
        out[(size_t)b * N + g] = acc;
    }
}

extern "C" void kernel_launch(void* const* d_in, const int* in_sizes, int n_in,
                              void* d_out, int out_size, void* d_ws, size_t ws_size,
                              hipStream_t stream)
{
    (void)in_sizes; (void)n_in; (void)out_size;
    const float* x      = (const float*)d_in[0];
    const float* conv_w = (const float*)d_in[1];
    const float* conv_b = (const float*)d_in[2];
    const float* w_ih1  = (const float*)d_in[3];
    const float* w_hh1  = (const float*)d_in[4];
    const float* b1     = (const float*)d_in[5];
    const float* w_ih2  = (const float*)d_in[6];
    const float* w_hh2  = (const float*)d_in[7];
    const float* b2     = (const float*)d_in[8];
    const float* w_ih3  = (const float*)d_in[9];
    const float* w_hh3  = (const float*)d_in[10];
    const float* b3     = (const float*)d_in[11];
    const float* fc1_w  = (const float*)d_in[12];
    const float* fc1_b  = (const float*)d_in[13];
    const float* fc2_w  = (const float*)d_in[14];
    const float* fc2_b  = (const float*)d_in[15];
    const float* fc3_w  = (const float*)d_in[16];
    const float* fc3_b  = (const float*)d_in[17];
    const float* fc4_w  = (const float*)d_in[18];
    const float* fc4_b  = (const float*)d_in[19];
    float* out = (float*)d_out;
    char*  base = (char*)d_ws;

    const size_t MB = 1ull << 20;

    // footprint: 2 fp16 Y buffers + 2 fp16 XW chunk buffers (double-buffered) + small
    auto need = [&](int s, int tc) -> size_t {
        size_t Bg = B_ALL / s;
        size_t YB = Bg * T_SZ * 256 * 2;
        size_t XW = (size_t)tc * Bg * 512 * 2 * 2;       // fp16, 2 dirs
        return 2 * YB + 2 * XW + 2 * MB;
    };

    int S = 8;
    for (int s : {1, 2, 4, 8}) {
        if (need(s, 32) <= ws_size) { S = s; break; }
    }
    int Tc = 32;
    while (Tc < 256 && need(S, Tc * 2) <= ws_size) Tc <<= 1;
    int lg = 0; while ((1 << lg) < Tc) lg++;
    int NC = T_SZ / Tc;

    int Bg = B_ALL / S;
    size_t YB  = (size_t)Bg * T_SZ * 256 * 2;
    size_t XWB = (size_t)Tc * Bg * 512 * 2 * 2;
    _Float16* Y1 = (_Float16*)base;
    _Float16* Y2 = (_Float16*)(base + YB);
    _Float16* X1 = Y2;                                   // aliased: X1 dead before Y2 written
    _Float16* XW[2] = { (_Float16*)(base + 2 * YB), (_Float16*)(base + 2 * YB + XWB) };
    float* sm  = (float*)(base + 2 * YB + 2 * XWB);
    float* Hs = sm;                   // 2*Bg*128
    float* Cs = Hs + 2 * Bg * 128;
    float* H3 = Cs + 2 * Bg * 128;    // Bg*128
    float* F1 = H3 + Bg * 128;        // Bg*512
    float* F2 = F1 + Bg * 512;        // Bg*256
    float* F3 = F2 + Bg * 256;        // Bg*128

    int MT = Bg * Tc / 128;

    for (int sp = 0; sp < S; ++sp) {
        int bg0 = sp * Bg;

        conv_relu_kernel<<<dim3(T_SZ / 4, Bg), 256, 0, stream>>>(x, conv_w, conv_b, X1, bg0);

        // ---- layer 1 (K=64, N=512, H=128, 2 dirs): X1 -> Y1 ----
        {
            int NT = 4, ndir = 2, Kl = 64, Nn = 512;
            int nProj = MT * NT * ndir, nRec = (Bg / 4) * ndir;
            fused_step<128, 8, true><<<nProj, 512, 0, stream>>>(
                XW[0], w_hh1, Y1, H3, Hs, Cs, Bg, Tc, lg, 0, 1, 0, 0, ndir,
                X1, w_ih1, b1, XW[0], Kl, Nn, 0, MT, NT);
            int par = 0;
            for (int ci = 0; ci < NC; ++ci) {
                int last = (ci == NC - 1);
                int grid = nRec + (last ? 0 : nProj);
                fused_step<128, 8, true><<<grid, 512, 0, stream>>>(
                    XW[par], w_hh1, Y1, H3, Hs, Cs, Bg, Tc, lg, ci * Tc, ci == 0, 0, nRec, ndir,
                    X1, w_ih1, b1, XW[1 - par], Kl, Nn, (ci + 1) * Tc, MT, NT);
                par ^= 1;
            }
        }
        // ---- layer 2 (K=256, N=512, H=128, 2 dirs): Y1 -> Y2 ----
        {
            int NT = 4, ndir = 2, Kl = 256, Nn = 512;
            int nProj = MT * NT * ndir, nRec = (Bg / 4) * ndir;
            fused_step<128, 8, true><<<nProj, 512, 0, stream>>>(
                XW[0], w_hh2, Y2, H3, Hs, Cs, Bg, Tc, lg, 0, 1, 0, 0, ndir,
                Y1, w_ih2, b2, XW[0], Kl, Nn, 0, MT, NT);
            int par = 0;
            for (int ci = 0; ci < NC; ++ci) {
                int last = (ci == NC - 1);
                int grid = nRec + (last ? 0 : nProj);
                fused_step<128, 8, true><<<grid, 512, 0, stream>>>(
                    XW[par], w_hh2, Y2, H3, Hs, Cs, Bg, Tc, lg, ci * Tc, ci == 0, 0, nRec, ndir,
                    Y1, w_ih2, b2, XW[1 - par], Kl, Nn, (ci + 1) * Tc, MT, NT);
                par ^= 1;
            }
        }
        // ---- layer 3 fwd (K=256, N=256, H=64, 1 dir): Y2 -> H3[:,0:64] ----
        {
            int NT = 2, ndir = 1, Kl = 256, Nn = 256;
            int nProj = MT * NT * ndir, nRec = (Bg / 4) * ndir;
            fused_step<64, 4, false><<<nProj, 512, 0, stream>>>(
                XW[0], w_hh3, nullptr, H3, Hs, Cs, Bg, Tc, lg, 0, 1, 0, 0, ndir,
                Y2, w_ih3, b3, XW[0], Kl, Nn, 0, MT, NT);
            int par = 0;
            for (int ci = 0; ci < NC; ++ci) {
                int last = (ci == NC - 1);
                int grid = nRec + (last ? 0 : nProj);
                fused_step<64, 4, false><<<grid, 512, 0, stream>>>(
                    XW[par], w_hh3, nullptr, H3, Hs, Cs, Bg, Tc, lg, ci * Tc, ci == 0, last, nRec, ndir,
                    Y2, w_ih3, b3, XW[1 - par], Kl, Nn, (ci + 1) * Tc, MT, NT);
                par ^= 1;
            }
        }
        lstm3_bwd_kernel<<<Bg, 256, 0, stream>>>(Y2, w_ih3, b3, H3);

        fc_kernel<<<Bg, 512, 128 * 4, stream>>>(H3, fc1_w, fc1_b, F1, 128, 512, 1);
        fc_kernel<<<Bg, 256, 512 * 4, stream>>>(F1, fc2_w, fc2_b, F2, 512, 256, 1);
        fc_kernel<<<Bg, 128, 256 * 4, stream>>>(F2, fc3_w, fc3_b, F3, 256, 128, 1);
        fc_kernel<<<Bg, 64, 128 * 4, stream>>>(F3, fc4_w, fc4_b, out + (size_t)bg0 * 2, 128, 2, 0);
    }
}